// Round 18
// baseline (185.573 us; speedup 1.0000x reference)
//
#include <hip/hip_runtime.h>
#include <hip/hip_fp16.h>

// N=524288 points, T=32 textures, C=7 channels, R=512.
// out[n,c] = sum_corner w_corner(n) * sum_t mw[n,t] * tex[t,c,y_k,x_k]
//
// v13: v12 UNFUSED (the fusion interfered: prep_fused=135us, no overlap).
//   1) zero_cursor
//   2) scatter_replicas: direct atomic, 4 replica cursors/bucket (n&3),
//      each on its own 64B line -> chain depth 32 (was 128).
//   3) transpose_tex_h: v2b's proven 61us transpose.
//   4) mix_tile: v12's (replica segment map), measured ~45us.

#define RR 512
#define TT 32
#define CC 7
#define NBK 4096                 // 64 x-tiles * 64 y-tiles (8x8 texels)
#define NREP 4                   // cursor replicas per bucket
#define CAPR 64                  // slots per replica (mean 32, +5.7 sigma)
#define CHUNKS_PER_C 324         // 9*9 positions * 4 uint4
#define CSTRIDE 325              // padded channel stride in uint4

typedef float fx2 __attribute__((ext_vector_type(2)));
typedef float fx4 __attribute__((ext_vector_type(4)));
typedef _Float16 h2 __attribute__((ext_vector_type(2)));

// ---------------- zero the strided replica cursors ----------------
__global__ __launch_bounds__(256) void zero_cursor(int* __restrict__ cursor) {
    cursor[blockIdx.x * 256 + threadIdx.x] = 0;   // grid 1024 -> 262144 ints
}

// ---------------- scatter: direct atomic, replicated strided cursors ----------------
__global__ __launch_bounds__(256) void scatter_replicas(const fx2* __restrict__ tc2,
                                                        fx4* __restrict__ recs,
                                                        int* __restrict__ cursor, int N) {
    int n = blockIdx.x * 256 + threadIdx.x;
    if (n >= N) return;
    fx2 xy = tc2[n];
    float ix = ((xy.x + 1.0f) * 512.0f - 1.0f) * 0.5f;
    float iy = ((xy.y + 1.0f) * 512.0f - 1.0f) * 0.5f;
    int xi0 = (int)fminf(fmaxf(floorf(ix), 0.0f), 511.0f);
    int yi0 = (int)fminf(fmaxf(floorf(iy), 0.0f), 511.0f);
    int b = ((yi0 >> 3) << 6) | (xi0 >> 3);
    int br = (b << 2) | (n & 3);              // bucket-replica id
    int slot = atomicAdd(&cursor[br << 4], 1);
    if (slot < CAPR) {
        fx4 rec = {xy.x, xy.y, __int_as_float(n), 0.0f};
        recs[(size_t)br * CAPR + slot] = rec;
    }
}

// ---------------- transpose+convert: (T,C,R,R) f32 -> (C,R,R,T) fp16 ----------------
__global__ __launch_bounds__(256) void transpose_tex_h(const float* __restrict__ src,
                                                       __half2* __restrict__ dst2) {
    __shared__ float tile[32][33];   // [t][x], +1 pad
    int b   = blockIdx.x;
    int xb  = (b & 15) << 5;         // x tile base
    int y   = (b >> 4) & 511;
    int c   = b >> 13;               // 0..6
    int tid = threadIdx.x;
    int xl  = tid & 31;
    int tq  = tid >> 5;              // 0..7
#pragma unroll
    for (int p = 0; p < 4; ++p) {
        int t = tq + p * 8;
        tile[t][xl] = src[((t * 7 + c) * 512 + y) * 512 + xb + xl];
    }
    __syncthreads();
#pragma unroll
    for (int p = 0; p < 2; ++p) {
        int o  = tid + p * 256;      // 0..511
        int x2 = o >> 4;             // 0..31
        int th = o & 15;             // half2 slot (t pair)
        float lo = tile[2 * th][x2];
        float hi = tile[2 * th + 1][x2];
        dst2[((c * 512 + y) * 512 + xb + x2) * 16 + th] = __floats2half2_rn(lo, hi);
    }
}

// 16-h2 dot of one staged position against the point's fp16 mix weights
__device__ __forceinline__ float dot_pos(const uint4* __restrict__ T, int idx,
                                         const h2* __restrict__ mh) {
    float d = 0.0f;
#pragma unroll
    for (int q = 0; q < 4; ++q) {
        union { uint4 u; h2 h[4]; } U;
        U.u = T[idx + q];
#pragma unroll
        for (int j = 0; j < 4; ++j) {
#if __has_builtin(__builtin_amdgcn_fdot2)
            d = __builtin_amdgcn_fdot2(U.h[j], mh[q * 4 + j], d, false);
#else
            d += (float)U.h[j].x * (float)mh[q * 4 + j].x
               + (float)U.h[j].y * (float)mh[q * 4 + j].y;
#endif
        }
    }
    return d;
}

// ---------------- main: one block per tile, LDS-staged texture ----------------
__global__ __launch_bounds__(256) void mix_tile(const fx4* __restrict__ recs,
                                                const int* __restrict__ cnts,
                                                const fx4* __restrict__ mw4,
                                                const uint4* __restrict__ t16,
                                                float* __restrict__ out) {
    __shared__ uint4 TILE[7 * CSTRIDE];          // 36,400 B
    int k  = blockIdx.x;
    int tx = k & 63, ty = k >> 6;
    int X0 = tx << 3, Y0 = ty << 3;
    int tid = threadIdx.x;

    // stage halo'd tile: 7ch x 9 rows x 9 xpos x 64B
    for (int q = tid; q < 7 * CHUNKS_PER_C; q += 256) {
        int c  = q / CHUNKS_PER_C;
        int r  = q - c * CHUNKS_PER_C;
        int yy = r / 36;
        int rr = r - yy * 36;
        int gx = X0 + (rr >> 2); if (gx > 511) gx = 511;
        int gy = Y0 + yy;        if (gy > 511) gy = 511;
        TILE[q + c] = t16[(size_t)((((c << 9) + gy) << 9) | gx) * 4 + (rr & 3)];
    }
    __syncthreads();

    // replica segment counts and prefix offsets
    int kb = k << 2;
    int c0 = cnts[(kb + 0) << 4]; c0 = c0 > CAPR ? CAPR : c0;
    int c1 = cnts[(kb + 1) << 4]; c1 = c1 > CAPR ? CAPR : c1;
    int c2 = cnts[(kb + 2) << 4]; c2 = c2 > CAPR ? CAPR : c2;
    int c3 = cnts[(kb + 3) << 4]; c3 = c3 > CAPR ? CAPR : c3;
    int o1 = c0, o2 = c0 + c1, o3 = c0 + c1 + c2;
    int total = o3 + c3;
    size_t rb = (size_t)kb * CAPR;

    int sub = tid & 7;
    int c   = (sub == 7) ? 0 : sub;              // lane 7 duplicates c=0 (no store)
    int cbase = c * CSTRIDE;

    int g = tid >> 3;
    if (g >= total) return;

#define SEG_ADDR(gv)                                                         \
    ({ int _r = (gv >= o1) + (gv >= o2) + (gv >= o3);                        \
       int _st = (_r == 0) ? 0 : ((_r == 1) ? o1 : ((_r == 2) ? o2 : o3));   \
       rb + (size_t)_r * CAPR + (gv - _st); })

    fx4 rec = recs[SEG_ADDR(g)];
    int n = __float_as_int(rec.z);
    fx4 m[8];
#pragma unroll
    for (int j = 0; j < 8; ++j) m[j] = mw4[(size_t)n * 8 + j];

    while (true) {
        int g2 = g + 32;
        bool live2 = g2 < total;
        fx4 rec2 = rec;
        if (live2) rec2 = recs[SEG_ADDR(g2)];    // prefetch next rec

        // ---- process current point ----
        float ix = ((rec.x + 1.0f) * 512.0f - 1.0f) * 0.5f;
        float iy = ((rec.y + 1.0f) * 512.0f - 1.0f) * 0.5f;
        float x0f = floorf(ix), y0f = floorf(iy);
        float fxw = ix - x0f, fyw = iy - y0f;
        float gxw = 1.0f - fxw, gyw = 1.0f - fyw;
        float w00 = gxw * gyw, w10 = fxw * gyw, w01 = gxw * fyw, w11 = fxw * fyw;
        bool vx0 = (x0f >= 0.0f), vx1 = (x0f <= 510.0f);
        bool vy0 = (y0f >= 0.0f), vy1 = (y0f <= 510.0f);
        if (!(vx0 && vy0)) w00 = 0.0f;
        if (!(vx1 && vy0)) w10 = 0.0f;
        if (!(vx0 && vy1)) w01 = 0.0f;
        if (!(vx1 && vy1)) w11 = 0.0f;
        int xi0 = (int)fminf(fmaxf(x0f, 0.0f), 511.0f);
        int xi1 = (int)fminf(fmaxf(x0f + 1.0f, 0.0f), 511.0f);
        int yi0 = (int)fminf(fmaxf(y0f, 0.0f), 511.0f);
        int yi1 = (int)fminf(fmaxf(y0f + 1.0f, 0.0f), 511.0f);
        int xl0 = xi0 - X0, xl1 = xi1 - X0;
        int yl0 = yi0 - Y0, yl1 = yi1 - Y0;

        // fp16 mix weights for this point
        h2 mh[16];
#pragma unroll
        for (int j = 0; j < 8; ++j) {
            mh[2 * j]     = h2{(_Float16)m[j].x, (_Float16)m[j].y};
            mh[2 * j + 1] = h2{(_Float16)m[j].z, (_Float16)m[j].w};
        }

        int p00 = cbase + ((yl0 * 9 + xl0) << 2);
        int p10 = cbase + ((yl0 * 9 + xl1) << 2);
        int p01 = cbase + ((yl1 * 9 + xl0) << 2);
        int p11 = cbase + ((yl1 * 9 + xl1) << 2);
        float d = w00 * dot_pos(TILE, p00, mh)
                + w10 * dot_pos(TILE, p10, mh)
                + w01 * dot_pos(TILE, p01, mh)
                + w11 * dot_pos(TILE, p11, mh);

        int nst = n;

        // prefetch next mw (depends on rec2, overlaps with store/loop)
        int n2 = 0;
        if (live2) {
            n2 = __float_as_int(rec2.z);
#pragma unroll
            for (int j = 0; j < 8; ++j) m[j] = mw4[(size_t)n2 * 8 + j];
        }

        if (sub < 7) __builtin_nontemporal_store(d, &out[(size_t)nst * 7 + c]);

        if (!live2) break;
        rec = rec2; n = n2; g = g2;
    }
#undef SEG_ADDR
}

// ---------------- fallback (ws too small): naive, original layout ----------------
__global__ __launch_bounds__(256) void mix_naive(const float* __restrict__ tc,
                                                 const float* __restrict__ mw,
                                                 const float* __restrict__ tex,
                                                 float* __restrict__ out, int N) {
    int n = blockIdx.x * 256 + threadIdx.x;
    if (n >= N) return;
    float x = tc[2 * n], y = tc[2 * n + 1];
    float ix = ((x + 1.0f) * 512.0f - 1.0f) * 0.5f;
    float iy = ((y + 1.0f) * 512.0f - 1.0f) * 0.5f;
    float x0f = floorf(ix), y0f = floorf(iy);
    float fx = ix - x0f, fy = iy - y0f;
    float gx = 1.0f - fx, gy = 1.0f - fy;
    float wgt[4] = {gx * gy, fx * gy, gx * fy, fx * fy};
    bool vx0 = (x0f >= 0.0f), vx1 = (x0f <= 510.0f);
    bool vy0 = (y0f >= 0.0f), vy1 = (y0f <= 510.0f);
    if (!(vx0 && vy0)) wgt[0] = 0.0f;
    if (!(vx1 && vy0)) wgt[1] = 0.0f;
    if (!(vx0 && vy1)) wgt[2] = 0.0f;
    if (!(vx1 && vy1)) wgt[3] = 0.0f;
    int xi0 = (int)fminf(fmaxf(x0f, 0.0f), 511.0f);
    int xi1 = (int)fminf(fmaxf(x0f + 1.0f, 0.0f), 511.0f);
    int yi0 = (int)fminf(fmaxf(y0f, 0.0f), 511.0f);
    int yi1 = (int)fminf(fmaxf(y0f + 1.0f, 0.0f), 511.0f);
    int xs[4] = {xi0, xi1, xi0, xi1};
    int ys[4] = {yi0, yi0, yi1, yi1};

    float acc[7] = {0.f, 0.f, 0.f, 0.f, 0.f, 0.f, 0.f};
#pragma unroll
    for (int kk = 0; kk < 4; ++kk) {
        float wk = wgt[kk];
        int base = ys[kk] * 512 + xs[kk];
        for (int t = 0; t < 32; ++t) {
            float m = wk * mw[(size_t)n * 32 + t];
#pragma unroll
            for (int cc = 0; cc < 7; ++cc)
                acc[cc] = fmaf(m, tex[(t * 7 + cc) * 262144 + base], acc[cc]);
        }
    }
#pragma unroll
    for (int cc = 0; cc < 7; ++cc) out[(size_t)n * 7 + cc] = acc[cc];
}

extern "C" void kernel_launch(void* const* d_in, const int* in_sizes, int n_in,
                              void* d_out, int out_size, void* d_ws, size_t ws_size,
                              hipStream_t stream) {
    const float* tc  = (const float*)d_in[0];
    const float* mw  = (const float*)d_in[1];
    const float* tex = (const float*)d_in[2];
    float* out = (float*)d_out;
    int N = in_sizes[0] / 2;

    const size_t TEXB = (size_t)CC * RR * RR * TT * sizeof(__half);     // 117,440,512
    const size_t RECB = (size_t)NBK * NREP * CAPR * sizeof(fx4);        //  16,777,216
    const size_t CURB = (size_t)NBK * NREP * 16 * sizeof(int);          //   1,048,576
    const size_t need = TEXB + RECB + CURB;

    if (ws_size >= need) {
        char* ws = (char*)d_ws;
        __half2* wst = (__half2*)ws;
        fx4* recs = (fx4*)(ws + TEXB);
        int* cur  = (int*)(ws + TEXB + RECB);

        zero_cursor<<<NBK * NREP * 16 / 256, 256, 0, stream>>>(cur);
        scatter_replicas<<<(N + 255) / 256, 256, 0, stream>>>((const fx2*)tc, recs, cur, N);
        transpose_tex_h<<<7 * 512 * 16, 256, 0, stream>>>(tex, wst);
        mix_tile<<<NBK, 256, 0, stream>>>((const fx4*)recs, (const int*)cur,
                                          (const fx4*)mw, (const uint4*)wst, out);
    } else {
        mix_naive<<<(N + 255) / 256, 256, 0, stream>>>(tc, mw, tex, out, N);
    }
}

// Round 19
// 180.678 us; speedup vs baseline: 1.0271x; 1.0271x over previous
//
#include <hip/hip_runtime.h>
#include <hip/hip_fp16.h>

// N=524288 points, T=32 textures, C=7 channels, R=512.
// out[n,c] = sum_corner w_corner(n) * sum_t mw[n,t] * tex[t,c,y_k,x_k]
//
// v14: bucket sort rebuilt as an exact COUNTING SORT with no global
// return-value atomics (the ~60-77us scatter cost was the per-point
// device-scope atomicAdd return dependency):
//   K1 hist_pts:   per-chunk LDS histogram -> cnt[256][4096]
//   K2 col_prefix: in-place exclusive prefix over chunks, tot[b]
//   K3 scan_base:  LDS scan of tot -> base[4097]
//   K4 place_pts:  slot = base[b]+chunkoff[chunk][b]+LDSrank -> recs
// Then v2b transpose (61us) and v8-style mix_tile over exact segments.

#define RR 512
#define TT 32
#define CC 7
#define NBK 4096                 // 64x64 tiles of 8x8 texels
#define NCH 256                  // histogram chunks (1 block each, 2048 pts)
#define CPP 2048                 // points per chunk
#define CHUNKS_PER_C 324         // 9*9 positions * 4 uint4
#define CSTRIDE 325              // padded channel stride in uint4

typedef float fx2 __attribute__((ext_vector_type(2)));
typedef float fx4 __attribute__((ext_vector_type(4)));
typedef _Float16 h2 __attribute__((ext_vector_type(2)));

__device__ __forceinline__ int bucket_of(float x, float y) {
    float ix = ((x + 1.0f) * 512.0f - 1.0f) * 0.5f;
    float iy = ((y + 1.0f) * 512.0f - 1.0f) * 0.5f;
    int xi0 = (int)fminf(fmaxf(floorf(ix), 0.0f), 511.0f);
    int yi0 = (int)fminf(fmaxf(floorf(iy), 0.0f), 511.0f);
    return ((yi0 >> 3) << 6) | (xi0 >> 3);
}

// ---- K1: per-chunk histogram (LDS atomics only) ----
__global__ __launch_bounds__(256) void hist_pts(const fx2* __restrict__ tc2,
                                                int* __restrict__ cnt, int N) {
    __shared__ int h[NBK];
    int tid = threadIdx.x, ch = blockIdx.x;
    for (int q = tid; q < NBK; q += 256) h[q] = 0;
    __syncthreads();
    int base_n = ch * CPP;
#pragma unroll
    for (int i = 0; i < CPP / 256; ++i) {
        int n = base_n + i * 256 + tid;
        if (n < N) {
            fx2 xy = tc2[n];
            atomicAdd(&h[bucket_of(xy.x, xy.y)], 1);
        }
    }
    __syncthreads();
    for (int q = tid; q < NBK; q += 256) cnt[ch * NBK + q] = h[q];
}

// ---- K2: in-place exclusive prefix over chunks per bucket; tot[b] ----
__global__ __launch_bounds__(256) void col_prefix(int* __restrict__ cnt,
                                                  int* __restrict__ tot) {
    int b = blockIdx.x * 256 + threadIdx.x;   // 16 blocks -> 4096
    int s = 0;
    for (int ch = 0; ch < NCH; ++ch) {
        int v = cnt[ch * NBK + b];
        cnt[ch * NBK + b] = s;
        s += v;
    }
    tot[b] = s;
}

// ---- K3: exclusive scan of tot[4096] -> base[4097] ----
__global__ __launch_bounds__(256) void scan_base(const int* __restrict__ tot,
                                                 int* __restrict__ base) {
    __shared__ int buf[NBK];
    __shared__ int part[256];
    int tid = threadIdx.x;
#pragma unroll
    for (int i = 0; i < 16; ++i) buf[tid * 16 + i] = tot[tid * 16 + i];
    int s = 0;
#pragma unroll
    for (int i = 0; i < 16; ++i) s += buf[tid * 16 + i];
    part[tid] = s;
    __syncthreads();
    // Hillis-Steele inclusive scan over 256 partials
    for (int d = 1; d < 256; d <<= 1) {
        int v = (tid >= d) ? part[tid - d] : 0;
        __syncthreads();
        part[tid] += v;
        __syncthreads();
    }
    int run = part[tid] - s;                  // exclusive offset for this thread
#pragma unroll
    for (int i = 0; i < 16; ++i) {
        base[tid * 16 + i] = run;
        run += buf[tid * 16 + i];
    }
    if (tid == 255) base[NBK] = run;
}

// ---- K4: placement (LDS rank atomics only) ----
__global__ __launch_bounds__(256) void place_pts(const fx2* __restrict__ tc2,
                                                 const int* __restrict__ cnt,
                                                 const int* __restrict__ base,
                                                 fx4* __restrict__ recs, int N) {
    __shared__ int cur[NBK];
    int tid = threadIdx.x, ch = blockIdx.x;
    for (int q = tid; q < NBK; q += 256)
        cur[q] = base[q] + cnt[ch * NBK + q];
    __syncthreads();
    int base_n = ch * CPP;
#pragma unroll
    for (int i = 0; i < CPP / 256; ++i) {
        int n = base_n + i * 256 + tid;
        if (n < N) {
            fx2 xy = tc2[n];
            int slot = atomicAdd(&cur[bucket_of(xy.x, xy.y)], 1);
            fx4 rec = {xy.x, xy.y, __int_as_float(n), 0.0f};
            recs[slot] = rec;
        }
    }
}

// ---- transpose+convert: (T,C,R,R) f32 -> (C,R,R,T) fp16 (v2b, 61us) ----
__global__ __launch_bounds__(256) void transpose_tex_h(const float* __restrict__ src,
                                                       __half2* __restrict__ dst2) {
    __shared__ float tile[32][33];
    int b   = blockIdx.x;
    int xb  = (b & 15) << 5;
    int y   = (b >> 4) & 511;
    int c   = b >> 13;
    int tid = threadIdx.x;
    int xl  = tid & 31;
    int tq  = tid >> 5;
#pragma unroll
    for (int p = 0; p < 4; ++p) {
        int t = tq + p * 8;
        tile[t][xl] = src[((t * 7 + c) * 512 + y) * 512 + xb + xl];
    }
    __syncthreads();
#pragma unroll
    for (int p = 0; p < 2; ++p) {
        int o  = tid + p * 256;
        int x2 = o >> 4;
        int th = o & 15;
        dst2[((c * 512 + y) * 512 + xb + x2) * 16 + th] =
            __floats2half2_rn(tile[2 * th][x2], tile[2 * th + 1][x2]);
    }
}

// 16-h2 dot of one staged position against the point's fp16 mix weights
__device__ __forceinline__ float dot_pos(const uint4* __restrict__ T, int idx,
                                         const h2* __restrict__ mh) {
    float d = 0.0f;
#pragma unroll
    for (int q = 0; q < 4; ++q) {
        union { uint4 u; h2 h[4]; } U;
        U.u = T[idx + q];
#pragma unroll
        for (int j = 0; j < 4; ++j) {
#if __has_builtin(__builtin_amdgcn_fdot2)
            d = __builtin_amdgcn_fdot2(U.h[j], mh[q * 4 + j], d, false);
#else
            d += (float)U.h[j].x * (float)mh[q * 4 + j].x
               + (float)U.h[j].y * (float)mh[q * 4 + j].y;
#endif
        }
    }
    return d;
}

// ---- main: one block per tile, exact segment [base[k], base[k+1]) ----
__global__ __launch_bounds__(256) void mix_tile(const fx4* __restrict__ recs,
                                                const int* __restrict__ base,
                                                const fx4* __restrict__ mw4,
                                                const uint4* __restrict__ t16,
                                                float* __restrict__ out) {
    __shared__ uint4 TILE[7 * CSTRIDE];          // 36,400 B
    int k  = blockIdx.x;
    int tx = k & 63, ty = k >> 6;
    int X0 = tx << 3, Y0 = ty << 3;
    int tid = threadIdx.x;

    for (int q = tid; q < 7 * CHUNKS_PER_C; q += 256) {
        int c  = q / CHUNKS_PER_C;
        int r  = q - c * CHUNKS_PER_C;
        int yy = r / 36;
        int rr = r - yy * 36;
        int gx = X0 + (rr >> 2); if (gx > 511) gx = 511;
        int gy = Y0 + yy;        if (gy > 511) gy = 511;
        TILE[q + c] = t16[(size_t)((((c << 9) + gy) << 9) | gx) * 4 + (rr & 3)];
    }
    __syncthreads();

    int rbase = base[k];
    int cnt   = base[k + 1] - rbase;

    int sub = tid & 7;
    int c   = (sub == 7) ? 0 : sub;
    int cbase = c * CSTRIDE;

    int s = tid >> 3;
    if (s >= cnt) return;

    fx4 rec = recs[rbase + s];
    int n = __float_as_int(rec.z);
    fx4 m[8];
#pragma unroll
    for (int j = 0; j < 8; ++j) m[j] = mw4[(size_t)n * 8 + j];

    while (true) {
        int s2 = s + 32;
        bool live2 = s2 < cnt;
        fx4 rec2 = rec;
        if (live2) rec2 = recs[rbase + s2];

        float ix = ((rec.x + 1.0f) * 512.0f - 1.0f) * 0.5f;
        float iy = ((rec.y + 1.0f) * 512.0f - 1.0f) * 0.5f;
        float x0f = floorf(ix), y0f = floorf(iy);
        float fxw = ix - x0f, fyw = iy - y0f;
        float gxw = 1.0f - fxw, gyw = 1.0f - fyw;
        float w00 = gxw * gyw, w10 = fxw * gyw, w01 = gxw * fyw, w11 = fxw * fyw;
        bool vx0 = (x0f >= 0.0f), vx1 = (x0f <= 510.0f);
        bool vy0 = (y0f >= 0.0f), vy1 = (y0f <= 510.0f);
        if (!(vx0 && vy0)) w00 = 0.0f;
        if (!(vx1 && vy0)) w10 = 0.0f;
        if (!(vx0 && vy1)) w01 = 0.0f;
        if (!(vx1 && vy1)) w11 = 0.0f;
        int xi0 = (int)fminf(fmaxf(x0f, 0.0f), 511.0f);
        int xi1 = (int)fminf(fmaxf(x0f + 1.0f, 0.0f), 511.0f);
        int yi0 = (int)fminf(fmaxf(y0f, 0.0f), 511.0f);
        int yi1 = (int)fminf(fmaxf(y0f + 1.0f, 0.0f), 511.0f);
        int xl0 = xi0 - X0, xl1 = xi1 - X0;
        int yl0 = yi0 - Y0, yl1 = yi1 - Y0;

        h2 mh[16];
#pragma unroll
        for (int j = 0; j < 8; ++j) {
            mh[2 * j]     = h2{(_Float16)m[j].x, (_Float16)m[j].y};
            mh[2 * j + 1] = h2{(_Float16)m[j].z, (_Float16)m[j].w};
        }

        int p00 = cbase + ((yl0 * 9 + xl0) << 2);
        int p10 = cbase + ((yl0 * 9 + xl1) << 2);
        int p01 = cbase + ((yl1 * 9 + xl0) << 2);
        int p11 = cbase + ((yl1 * 9 + xl1) << 2);
        float d = w00 * dot_pos(TILE, p00, mh)
                + w10 * dot_pos(TILE, p10, mh)
                + w01 * dot_pos(TILE, p01, mh)
                + w11 * dot_pos(TILE, p11, mh);

        int nst = n;
        int n2 = 0;
        if (live2) {
            n2 = __float_as_int(rec2.z);
#pragma unroll
            for (int j = 0; j < 8; ++j) m[j] = mw4[(size_t)n2 * 8 + j];
        }

        if (sub < 7) __builtin_nontemporal_store(d, &out[(size_t)nst * 7 + c]);

        if (!live2) break;
        rec = rec2; n = n2; s = s2;
    }
}

// ---------------- fallback (ws too small): naive, original layout ----------------
__global__ __launch_bounds__(256) void mix_naive(const float* __restrict__ tc,
                                                 const float* __restrict__ mw,
                                                 const float* __restrict__ tex,
                                                 float* __restrict__ out, int N) {
    int n = blockIdx.x * 256 + threadIdx.x;
    if (n >= N) return;
    float x = tc[2 * n], y = tc[2 * n + 1];
    float ix = ((x + 1.0f) * 512.0f - 1.0f) * 0.5f;
    float iy = ((y + 1.0f) * 512.0f - 1.0f) * 0.5f;
    float x0f = floorf(ix), y0f = floorf(iy);
    float fx = ix - x0f, fy = iy - y0f;
    float gx = 1.0f - fx, gy = 1.0f - fy;
    float wgt[4] = {gx * gy, fx * gy, gx * fy, fx * fy};
    bool vx0 = (x0f >= 0.0f), vx1 = (x0f <= 510.0f);
    bool vy0 = (y0f >= 0.0f), vy1 = (y0f <= 510.0f);
    if (!(vx0 && vy0)) wgt[0] = 0.0f;
    if (!(vx1 && vy0)) wgt[1] = 0.0f;
    if (!(vx0 && vy1)) wgt[2] = 0.0f;
    if (!(vx1 && vy1)) wgt[3] = 0.0f;
    int xi0 = (int)fminf(fmaxf(x0f, 0.0f), 511.0f);
    int xi1 = (int)fminf(fmaxf(x0f + 1.0f, 0.0f), 511.0f);
    int yi0 = (int)fminf(fmaxf(y0f, 0.0f), 511.0f);
    int yi1 = (int)fminf(fmaxf(y0f + 1.0f, 0.0f), 511.0f);
    int xs[4] = {xi0, xi1, xi0, xi1};
    int ys[4] = {yi0, yi0, yi1, yi1};

    float acc[7] = {0.f, 0.f, 0.f, 0.f, 0.f, 0.f, 0.f};
#pragma unroll
    for (int kk = 0; kk < 4; ++kk) {
        float wk = wgt[kk];
        int base = ys[kk] * 512 + xs[kk];
        for (int t = 0; t < 32; ++t) {
            float m = wk * mw[(size_t)n * 32 + t];
#pragma unroll
            for (int cc = 0; cc < 7; ++cc)
                acc[cc] = fmaf(m, tex[(t * 7 + cc) * 262144 + base], acc[cc]);
        }
    }
#pragma unroll
    for (int cc = 0; cc < 7; ++cc) out[(size_t)n * 7 + cc] = acc[cc];
}

extern "C" void kernel_launch(void* const* d_in, const int* in_sizes, int n_in,
                              void* d_out, int out_size, void* d_ws, size_t ws_size,
                              hipStream_t stream) {
    const float* tc  = (const float*)d_in[0];
    const float* mw  = (const float*)d_in[1];
    const float* tex = (const float*)d_in[2];
    float* out = (float*)d_out;
    int N = in_sizes[0] / 2;

    const size_t TEXB = (size_t)CC * RR * RR * TT * sizeof(__half);   // 117,440,512
    const size_t RECB = (size_t)N * sizeof(fx4);                      //   8,388,608
    const size_t CNTB = (size_t)NCH * NBK * sizeof(int);              //   4,194,304
    const size_t TOTB = (size_t)NBK * sizeof(int);                    //      16,384
    const size_t BASB = (size_t)(NBK + 64) * sizeof(int);             //      16,640
    const size_t need = TEXB + RECB + CNTB + TOTB + BASB;

    if (ws_size >= need) {
        char* ws = (char*)d_ws;
        __half2* wst = (__half2*)ws;
        fx4* recs = (fx4*)(ws + TEXB);
        int* cnt  = (int*)(ws + TEXB + RECB);
        int* tot  = (int*)(ws + TEXB + RECB + CNTB);
        int* base = (int*)(ws + TEXB + RECB + CNTB + TOTB);

        hist_pts<<<NCH, 256, 0, stream>>>((const fx2*)tc, cnt, N);
        col_prefix<<<NBK / 256, 256, 0, stream>>>(cnt, tot);
        scan_base<<<1, 256, 0, stream>>>(tot, base);
        place_pts<<<NCH, 256, 0, stream>>>((const fx2*)tc, cnt, base, recs, N);
        transpose_tex_h<<<7 * 512 * 16, 256, 0, stream>>>(tex, wst);
        mix_tile<<<NBK, 256, 0, stream>>>((const fx4*)recs, (const int*)base,
                                          (const fx4*)mw, (const uint4*)wst, out);
    } else {
        mix_naive<<<(N + 255) / 256, 256, 0, stream>>>(tc, mw, tex, out, N);
    }
}